// Round 4
// baseline (1291.639 us; speedup 1.0000x reference)
//
#include <hip/hip_runtime.h>

// CATSCluster: fused 3-stream MLP (768->256->128) + combine on MI355X.
// Round N+4: break the barrier lockstep.
//  Round-3 counters: spills gone, HBM 734 GB/s, MfmaUtil 23.5, VALU 16 ->
//  ~60% stall with both pipes empty = latency-bound with phase-synchronized
//  waves (2 barrier domains/CU, 8-wave blocks leave each barrier together,
//  B-load L2 latency ~200cy x 8 serial pairs/interval rides every wave).
//  Fix: 256-thread blocks, 32-row tiles (wave tile 32x64 -- identical
//  per-wave MFMA/load/split ratios), grid 2048. LDS 35.8KB -> 4 blocks/CU:
//  each SIMD gets 4 waves from 4 INDEPENDENT blocks -> phases interleave,
//  B-latency of one wave hides under MFMAs of another.
//  Plus: B-pair 1-ahead prefetch (2 pairs live, fits 128-reg cap),
//  s_setprio(1) around MFMA clusters (T5: positive with phase diversity).
// Numerics bitwise-identical: split-precision bf16 MFMA, 3 terms GEMM1,
// 2 terms GEMM2, same per-accumulator MFMA order, fp32 combine.

typedef short short8 __attribute__((ext_vector_type(8)));   // 8 x bf16 (4 VGPRs)
typedef float f32x4 __attribute__((ext_vector_type(4)));    // MFMA accumulator

// d_ws layout (in unsigned short elements)
#define W1H_OFF 0u
#define W1L_OFF 196608u
#define W3H_OFF 393216u
#define W3L_OFF 589824u
#define W2H_OFF 786432u
#define W2L_OFF 819200u
#define W4H_OFF 851968u
#define W4L_OFF 884736u
// lo plane = hi plane + 196608 (W1/W3) or + 32768 (W2/W4)

__device__ __forceinline__ unsigned short bf16_rne(float f) {
  unsigned int u = __float_as_uint(f);
  u += 0x7FFFu + ((u >> 16) & 1u);      // round-to-nearest-even
  return (unsigned short)(u >> 16);
}

__device__ __forceinline__ void split_bf16(float f, unsigned short& h, unsigned short& l) {
  h = bf16_rne(f);
  float fh = __uint_as_float(((unsigned int)h) << 16);
  l = bf16_rne(f - fh);                 // residual; |x - hi - lo| ~ 2^-18 |x|
}

__device__ __forceinline__ void pack_split4(const float4 v, uint2& ph, uint2& pl) {
  unsigned short h0,h1,h2,h3,l0,l1,l2,l3;
  split_bf16(v.x,h0,l0); split_bf16(v.y,h1,l1);
  split_bf16(v.z,h2,l2); split_bf16(v.w,h3,l3);
  ph.x = (unsigned)h0 | ((unsigned)h1 << 16); ph.y = (unsigned)h2 | ((unsigned)h3 << 16);
  pl.x = (unsigned)l0 | ((unsigned)l1 << 16); pl.y = (unsigned)l2 | ((unsigned)l3 << 16);
}

__global__ __launch_bounds__(256) void prep_weights(
    const float* __restrict__ W1, const float* __restrict__ W2,
    const float* __restrict__ W3, const float* __restrict__ W4,
    unsigned short* __restrict__ ws)
{
  int i = blockIdx.x * 256 + threadIdx.x;
  if (i < 196608) {
    unsigned short h, l;
    split_bf16(W1[i], h, l); ws[W1H_OFF + i] = h; ws[W1L_OFF + i] = l;
    split_bf16(W3[i], h, l); ws[W3H_OFF + i] = h; ws[W3L_OFF + i] = l;
    if (i < 32768) {
      split_bf16(W2[i], h, l); ws[W2H_OFF + i] = h; ws[W2L_OFF + i] = l;
      split_bf16(W4[i], h, l); ws[W4H_OFF + i] = h; ws[W4L_OFF + i] = l;
    }
  }
}

#define STRIDE_A 72    // shorts per A-row in LDS (64 used; 144B stride -> uniform 8-group banks)
#define STRIDE_H 264   // shorts per H-row in LDS (256 used; 528B stride -> uniform)

__global__ __launch_bounds__(256, 4) void catsc_main(
    const float* __restrict__ X, const unsigned short* __restrict__ ws,
    const float* __restrict__ W5, float* __restrict__ out)
{
  __shared__ short lsA[2][2][32 * STRIDE_A]; // [dbuf][hi/lo][row*72+k]  18,432 B
  __shared__ short lsH[32 * STRIDE_H];       // relu(h) as bf16          16,896 B
  __shared__ float lsPart[4][32];            // cross-wave dot partials     512 B
                                             // total 35,840 B -> 4 blocks/CU

  const int tid  = threadIdx.x;
  const int wave = tid >> 6;      // 0..3
  const int lane = tid & 63;
  const int l15  = lane & 15;
  const int q    = lane >> 4;     // quad index 0..3
  const int blk  = blockIdx.x;    // 0..2047, 32 rows each; 128 blocks per n (4096/32)

  // X_data is (16, 4097, 2304); skip row 0 of each n.
  const float* Xb = X + (size_t)((blk >> 7) * 4097 + 1 + ((blk & 127) << 5)) * 2304;

  // cooperative staging: thread -> (row, 8-float segment); 256 thr cover 32x64/interval
  const int srow = tid >> 3;        // 0..31
  const int scol = (tid & 7) << 3;  // float offset 0,8,...,56 within 64-col interval
  const float* Xs = Xb + (size_t)srow * 2304 + scol;
  short* lsW = &lsA[0][0][0];       // raw base for staging writes
  const int sidx = srow * STRIDE_A + scol;   // short index within one lsA plane
  const int PLANE = 32 * STRIDE_A;           // shorts per [hi/lo] plane

  // hoisted lane-invariant offsets
  const int arow = l15 * STRIDE_A + q * 8;                    // A-frag LDS offset
  const size_t bwl = (size_t)(wave * 64 + l15) * 768 + q * 8; // B1 lane/wave base
  const size_t cwl = (size_t)(wave * 32 + l15) * 256 + q * 8; // B2 lane/wave base
  const int hrow = l15 * STRIDE_H + q * 8;                    // H-frag LDS offset

  f32x4 zp[2][2];  // after p1: zp1 ; after p2: |zp1-zp2| ; consumed by q-combine

  // T14: interval-0 X data for stream 0 (p1, cols 768..) issued at kernel top
  float4 vP0 = *(const float4*)(Xs + 768);
  float4 vP1 = *(const float4*)(Xs + 768 + 4);

#pragma unroll 1
  for (int s = 0; s < 3; ++s) {
    // stream order: s=0 -> p1 (768..), s=1 -> p2 (1536..), s=2 -> q (0..)
    const int so = (s == 0) ? 768 : (s == 1) ? 1536 : 0;
    const unsigned short* B1h = ws + (s == 2 ? W3H_OFF : W1H_OFF) + bwl;
    const unsigned short* B2h = ws + (s == 2 ? W4H_OFF : W2H_OFF) + cwl;

    f32x4 acc[2][4];
#pragma unroll
    for (int m = 0; m < 2; ++m)
#pragma unroll
      for (int n = 0; n < 4; ++n)
        acc[m][n] = f32x4{0.f, 0.f, 0.f, 0.f};

    // ---- prologue: stage interval 0 (from the early-issued vP regs) ----
    {
      uint2 ph, pl;
      pack_split4(vP0, ph, pl);
      *(uint2*)&lsW[sidx]         = ph;
      *(uint2*)&lsW[PLANE + sidx] = pl;
      pack_split4(vP1, ph, pl);
      *(uint2*)&lsW[sidx + 4]         = ph;
      *(uint2*)&lsW[PLANE + sidx + 4] = pl;
    }
    __syncthreads();

    // ---- GEMM1: 12 intervals of K=64, double-buffered, depth-1 X prefetch ----
    for (int p = 0; p < 12; ++p) {
      const int b = p & 1;
      // issue X loads for interval p+1 now; consumed at end of this interval
      float4 vB0, vB1;
      if (p + 1 < 12) {
        vB0 = *(const float4*)(Xs + so + (p + 1) * 64);
        vB1 = *(const float4*)(Xs + so + (p + 1) * 64 + 4);
      }
      const short* As0 = &lsA[b][0][arow];
      const short* As1 = &lsA[b][1][arow];

#pragma unroll
      for (int sub = 0; sub < 2; ++sub) {
        // A fragments for both m-tiles (16 regs)
        short8 Ah[2], Al[2];
#pragma unroll
        for (int mm = 0; mm < 2; ++mm) {
          const int a = mm * 16 * STRIDE_A + sub * 32;
          Ah[mm] = *(const short8*)(As0 + a);
          Al[mm] = *(const short8*)(As1 + a);
        }
        // B pairs with 1-ahead prefetch (2 pairs live = 16 regs).
        // per-acc order: Ah*Bh, Ah*Bl, Al*Bh -- bitwise-identical to before.
        const unsigned short* bp0 = B1h + p * 64 + sub * 32;
        short8 Bh = *(const short8*)bp0;
        short8 Bl = *(const short8*)(bp0 + 196608);
        __builtin_amdgcn_s_setprio(1);
#pragma unroll
        for (int n = 0; n < 4; ++n) {
          short8 BhN, BlN;
          if (n < 3) {
            const unsigned short* bp = B1h + (size_t)(n + 1) * 12288 + p * 64 + sub * 32;
            BhN = *(const short8*)bp;
            BlN = *(const short8*)(bp + 196608);
          }
          acc[0][n] = __builtin_amdgcn_mfma_f32_16x16x32_bf16(Ah[0], Bh, acc[0][n], 0, 0, 0);
          acc[1][n] = __builtin_amdgcn_mfma_f32_16x16x32_bf16(Ah[1], Bh, acc[1][n], 0, 0, 0);
          acc[0][n] = __builtin_amdgcn_mfma_f32_16x16x32_bf16(Ah[0], Bl, acc[0][n], 0, 0, 0);
          acc[1][n] = __builtin_amdgcn_mfma_f32_16x16x32_bf16(Ah[1], Bl, acc[1][n], 0, 0, 0);
          acc[0][n] = __builtin_amdgcn_mfma_f32_16x16x32_bf16(Al[0], Bh, acc[0][n], 0, 0, 0);
          acc[1][n] = __builtin_amdgcn_mfma_f32_16x16x32_bf16(Al[1], Bh, acc[1][n], 0, 0, 0);
          Bh = BhN; Bl = BlN;
        }
        __builtin_amdgcn_s_setprio(0);
      }

      // split the prefetched interval p+1 into the other LDS buffer
      if (p + 1 < 12) {
        short* dst = lsW + (b ^ 1) * (2 * PLANE);
        uint2 ph, pl;
        pack_split4(vB0, ph, pl);
        *(uint2*)&dst[sidx]         = ph;
        *(uint2*)&dst[PLANE + sidx] = pl;
        pack_split4(vB1, ph, pl);
        *(uint2*)&dst[sidx + 4]         = ph;
        *(uint2*)&dst[PLANE + sidx + 4] = pl;
      }
      __syncthreads();
    }

    // ---- H = relu(acc) -> LDS as bf16 (C-layout: col=l15, row=q*4+i) ----
#pragma unroll
    for (int m = 0; m < 2; ++m)
#pragma unroll
      for (int n = 0; n < 4; ++n) {
        int col = (wave * 4 + n) * 16 + l15;
#pragma unroll
        for (int i = 0; i < 4; ++i) {
          int row = m * 16 + q * 4 + i;
          lsH[row * STRIDE_H + col] = bf16_rne(fmaxf(acc[m][n][i], 0.f));
        }
      }
    __syncthreads();

    // T14: issue next stream's interval-0 X loads now; consumed after GEMM2
    if (s < 2) {
      const int nso = (s == 0) ? 1536 : 0;
      vP0 = *(const float4*)(Xs + nso);
      vP1 = *(const float4*)(Xs + nso + 4);
    }

    // ---- GEMM2: (32 x 256) x (256 -> 128), H bf16 x W split (2 terms);
    //      4 waves x 32 output cols each ----
    f32x4 acc2[2][2];
#pragma unroll
    for (int m = 0; m < 2; ++m)
#pragma unroll
      for (int n2 = 0; n2 < 2; ++n2)
        acc2[m][n2] = f32x4{0.f, 0.f, 0.f, 0.f};

    for (int c2 = 0; c2 < 8; ++c2) {
      short8 Ha[2];
#pragma unroll
      for (int m = 0; m < 2; ++m)
        Ha[m] = *(const short8*)&lsH[m * 16 * STRIDE_H + hrow + c2 * 32];
#pragma unroll
      for (int n2 = 0; n2 < 2; ++n2) {
        const unsigned short* cp = B2h + n2 * 4096 + c2 * 32;
        short8 Ch = *(const short8*)cp;
        short8 Cl = *(const short8*)(cp + 32768);
        acc2[0][n2] = __builtin_amdgcn_mfma_f32_16x16x32_bf16(Ha[0], Ch, acc2[0][n2], 0, 0, 0);
        acc2[1][n2] = __builtin_amdgcn_mfma_f32_16x16x32_bf16(Ha[1], Ch, acc2[1][n2], 0, 0, 0);
        acc2[0][n2] = __builtin_amdgcn_mfma_f32_16x16x32_bf16(Ha[0], Cl, acc2[0][n2], 0, 0, 0);
        acc2[1][n2] = __builtin_amdgcn_mfma_f32_16x16x32_bf16(Ha[1], Cl, acc2[1][n2], 0, 0, 0);
      }
    }

    // ---- per-stream epilogue: minimal cross-stream register state ----
    if (s == 0) {                       // zp1
#pragma unroll
      for (int m = 0; m < 2; ++m)
#pragma unroll
        for (int n2 = 0; n2 < 2; ++n2)
#pragma unroll
          for (int i = 0; i < 4; ++i)
            zp[m][n2][i] = fmaxf(acc2[m][n2][i], 0.f);
    } else if (s == 1) {                // |zp1 - zp2|
#pragma unroll
      for (int m = 0; m < 2; ++m)
#pragma unroll
        for (int n2 = 0; n2 < 2; ++n2)
#pragma unroll
          for (int i = 0; i < 4; ++i)
            zp[m][n2][i] = fabsf(zp[m][n2][i] - fmaxf(acc2[m][n2][i], 0.f));
    } else {                            // q: combine + W5 dot immediately
      const float w5c0 = W5[wave * 32 + l15];
      const float w5c1 = W5[wave * 32 + 16 + l15];
#pragma unroll
      for (int m = 0; m < 2; ++m)
#pragma unroll
        for (int i = 0; i < 4; ++i) {
          float v = fmaxf(acc2[m][0][i], 0.f) * zp[m][0][i] * w5c0
                  + fmaxf(acc2[m][1][i], 0.f) * zp[m][1][i] * w5c1;
          // reduce over the 16 cols held by l15 (within each quad group)
          v += __shfl_xor(v, 1);
          v += __shfl_xor(v, 2);
          v += __shfl_xor(v, 4);
          v += __shfl_xor(v, 8);
          if (l15 == 0) lsPart[wave][m * 16 + q * 4 + i] = v;
        }
    }
    // No barrier needed before next stream's lsA prologue writes: every wave
    // is past the post-H __syncthreads (so past all lsA reads of this
    // stream); prologue touches lsA only, GEMM2 reads lsH only (disjoint),
    // and new lsA data is only read after the next stream's own barrier.
  }

  __syncthreads();
  if (tid < 32) {
    float sum = lsPart[0][tid] + lsPart[1][tid] + lsPart[2][tid] + lsPart[3][tid];
    out[(size_t)blk * 32 + tid] = tanhf(fmaxf(sum, 0.f));
  }
}

extern "C" void kernel_launch(void* const* d_in, const int* in_sizes, int n_in,
                              void* d_out, int out_size, void* d_ws, size_t ws_size,
                              hipStream_t stream) {
  const float* X  = (const float*)d_in[0];
  const float* W1 = (const float*)d_in[1];
  const float* W2 = (const float*)d_in[2];
  const float* W3 = (const float*)d_in[3];
  const float* W4 = (const float*)d_in[4];
  const float* W5 = (const float*)d_in[5];
  float* out = (float*)d_out;
  unsigned short* ws = (unsigned short*)d_ws;  // needs 1.75 MB

  prep_weights<<<dim3(768), dim3(256), 0, stream>>>(W1, W2, W3, W4, ws);
  catsc_main<<<dim3(2048), dim3(256), 0, stream>>>(X, ws, W5, out);
}